// Round 1
// baseline (8460.490 us; speedup 1.0000x reference)
//
#include <hip/hip_runtime.h>
#include <math.h>

#define NLAT_I 240
#define NLON_I 480
#define NLAT_O 361
#define NLON_O 720
#define CI_N 32
#define CO_N 32
#define K_N 7
#define WOFF 10
#define WLAT 21

#define PI_F 3.14159265358979323846f
#define TWOPI_F 6.28318530717958647692f
#define DLAT_V (PI_F / 360.0f)
#define DPHI_V (TWOPI_F / 720.0f)
#define CUTOFF_V (3.25f * PI_F / 120.0f)
#define DR_V (CUTOFF_V / 3.0f)
#define IDR_V (1.0f / DR_V)
#define DPH_V (TWOPI_F / 3.0f)
#define IDPH_V (1.0f / DPH_V)
#define QF_V (DLAT_V * DPHI_V)

// tiling
#define PT 80          // lon columns per workgroup (9 tiles * 80 = 720)
#define NTILE 9
#define BCH 180        // beta chunk
#define XSTR 265       // xu LDS row stride (>= BCH+79, odd-ish for banks)
#define GSTR 85        // G dump stride (odd for banks)

// ---------------- psi evaluation (shared by scale + main kernels) -----------
__device__ __forceinline__ void psi_eval(float ct, float st, float cg, float sg,
                                         float q, float bang, float v[7]) {
  float sb, cb;
  sincosf(bang, &sb, &cb);
  // chordal distance -> arc (better conditioned than acos near r=0)
  float dx = sg * cb - st;
  float dy = sg * sb;
  float dz = cg - ct;
  float c2 = dx * dx + dy * dy + dz * dz;
  float r = 2.0f * asinf(fminf(1.0f, 0.5f * sqrtf(c2)));
  if (r <= CUTOFF_V) {
    float xx = ct * cb * sg - st * cg;
    float yy = sb * sg;
    float phi = atan2f(yy, xx);
    if (phi < 0.0f) phi += TWOPI_F;
    v[0] = fmaxf(0.0f, 1.0f - r * IDR_V) * q;
#pragma unroll
    for (int k = 1; k < 7; ++k) {
      const float irdr = (float)(1 + (k - 1) / 3) * DR_V;
      const float ipph = (float)((k - 1) % 3) * DPH_V;
      float rad = fmaxf(0.0f, 1.0f - fabsf(r - irdr) * IDR_V);
      float dd = fabsf(phi - ipph);
      dd = fminf(dd, TWOPI_F - dd);
      float az = fmaxf(0.0f, 1.0f - dd * IDPH_V);
      v[k] = rad * az * q;
    }
  } else {
#pragma unroll
    for (int k = 0; k < 7; ++k) v[k] = 0.0f;
  }
}

// ---------------- kernel 1: bilinear upsample -------------------------------
__global__ void upsample_kernel(const float* __restrict__ x, float* __restrict__ xu) {
  int idx = blockIdx.x * 256 + threadIdx.x;
  if (idx >= CI_N * NLAT_O * NLON_O) return;
  int p = idx % NLON_O;
  int r = idx / NLON_O;
  int t = r % NLAT_O;
  int i = r / NLAT_O;

  double post = (double)t * (239.0 / 360.0);
  int i0 = (int)floor(post);
  if (i0 < 0) i0 = 0;
  if (i0 > NLAT_I - 1) i0 = NLAT_I - 1;
  int i1 = i0 + 1; if (i1 > NLAT_I - 1) i1 = NLAT_I - 1;
  float wt = (float)(post - (double)i0);

  double posp = (double)p * (2.0 / 3.0);
  double j0f = floor(posp);
  int j0 = ((int)j0f) % NLON_I;
  int j1 = (j0 + 1) % NLON_I;
  float wp = (float)(posp - j0f);

  const float* xi = x + (size_t)i * (NLAT_I * NLON_I);
  float a = xi[i0 * NLON_I + j0];
  float b = xi[i0 * NLON_I + j1];
  float c = xi[i1 * NLON_I + j0];
  float d = xi[i1 * NLON_I + j1];
  float l0 = (1.0f - wt) * a + wt * c;
  float l1 = (1.0f - wt) * b + wt * d;
  xu[idx] = (1.0f - wp) * l0 + wp * l1;
}

// ---------------- kernel 2: per-(k,t) normalization scales ------------------
__global__ void scale_kernel(float* __restrict__ recip) {
  int t = blockIdx.x;
  int tid = threadIdx.x;
  float th = (float)t * DLAT_V;
  float st, ct;
  sincosf(th, &st, &ct);
  float acc[7];
#pragma unroll
  for (int k = 0; k < 7; ++k) acc[k] = 0.0f;

  for (int d = 0; d < WLAT; ++d) {
    int tp = t + d - WOFF;
    if (tp < 0 || tp > NLAT_O - 1) continue;
    float ga = (float)tp * DLAT_V;
    float sg, cg;
    sincosf(ga, &sg, &cg);
    float q = sg * QF_V;
    for (int j = tid; j < NLON_O; j += 256) {
      float v[7];
      psi_eval(ct, st, cg, sg, q, (float)j * DPHI_V, v);
#pragma unroll
      for (int k = 0; k < 7; ++k) acc[k] += v[k];
    }
  }
#pragma unroll
  for (int k = 0; k < 7; ++k) {
    float a = acc[k];
    for (int off = 32; off > 0; off >>= 1) a += __shfl_down(a, off, 64);
    acc[k] = a;
  }
  __shared__ float red[4][7];
  int wid = tid >> 6;
  if ((tid & 63) == 0) {
#pragma unroll
    for (int k = 0; k < 7; ++k) red[wid][k] = acc[k];
  }
  __syncthreads();
  if (tid == 0) {
#pragma unroll
    for (int k = 0; k < 7; ++k) {
      float s = red[0][k] + red[1][k] + red[2][k] + red[3][k];
      recip[t * 7 + k] = 1.0f / fmaxf(s, 1e-8f);
    }
  }
}

// ---------------- kernel 3: fused sparse conv + channel GEMM ----------------
#define KROW(R, PK, X0, X1, X2, X3, X4)                                   \
  if ((PK) != 0.0f) {                                                     \
    R[0] += (PK) * (X0); R[1] += (PK) * (X1); R[2] += (PK) * (X2);        \
    R[3] += (PK) * (X3); R[4] += (PK) * (X4);                             \
  }

__global__ __launch_bounds__(256) void disco_kernel(
    const float* __restrict__ xu, const float* __restrict__ recip,
    const float* __restrict__ w, float* __restrict__ y) {
  const int t = blockIdx.x;
  const int p0 = blockIdx.y * PT;
  const int tid = threadIdx.x;

  __shared__ __align__(16) union SMem {
    struct {
      float xu[16 * XSTR];     // staged xu rows (one i-half, one d)
      float ps[BCH * 8];       // psi: [chunk_idx][k0..k6, any]
    } m;
    float g[7 * 16 * GSTR];    // G dump for GEMM phase
  } sm;
  __shared__ int sBd[WLAT];

  // ---- per-d lon window half-width ----
  if (tid < WLAT) {
    int d = tid;
    int tp = t + d - WOFF;
    int B = -1;
    if (tp >= 0 && tp <= NLAT_O - 1) {
      float th = (float)t * DLAT_V, ga = (float)tp * DLAT_V;
      float st = sinf(th), ctb = cosf(th), sg = sinf(ga), cgb = cosf(ga);
      float den = st * sg;
      float num = cosf(CUTOFF_V) - ctb * cgb;
      if (den < 1e-9f) {
        B = (fabsf(th - ga) <= CUTOFF_V) ? 360 : -1;
      } else if (num >= den) {
        B = -1;                              // r(beta=0) >= CUTOFF -> empty
      } else if (num <= -den) {
        B = 360;                             // whole circle inside
      } else {
        float E = num / den;
        B = (int)ceilf(acosf(E) * (1.0f / DPHI_V)) + 1;  // +1 safety margin
        if (B > 360) B = 360;
      }
    }
    sBd[d] = B;
  }
  __syncthreads();

  float Ga[7][5] = {{0.0f}};   // G accumulators, i-half 0
  float Gb[7][5] = {{0.0f}};   // i-half 1
  const int il = tid & 15;     // i within half
  const int cl = tid >> 4;     // 0..15 -> 5-col chunk
  const int pbase = 5 * cl;

  float tht = (float)t * DLAT_V;
  float stv, ctv;
  sincosf(tht, &stv, &ctv);

  for (int d = 0; d < WLAT; ++d) {
    int Bd = sBd[d];
    if (Bd < 0) continue;
    int tp = t + d - WOFF;
    float ga = (float)tp * DLAT_V;
    float sgv, cgv;
    sincosf(ga, &sgv, &cgv);
    float q = sgv * QF_V;
    int lo = -Bd;
    int hi = (Bd >= 360) ? 359 : Bd;   // avoid double-counting beta=+-360

    for (int blo = lo; blo <= hi; blo += BCH) {
      int bhi = blo + BCH - 1; if (bhi > hi) bhi = hi;
      int cnt = bhi - blo + 1;
      int W = cnt + PT - 1;            // staged columns

      // stage psi for this (d, chunk)
      for (int ix = tid; ix < cnt; ix += 256) {
        int b = blo + ix;
        float v[7];
        psi_eval(ctv, stv, cgv, sgv, q, (float)b * DPHI_V, v);
        float s = 0.0f;
        float vn[7];
#pragma unroll
        for (int k = 0; k < 7; ++k) { vn[k] = v[k] * recip[t * 7 + k]; s += vn[k]; }
        float4 A, B4;
        A.x = vn[0]; A.y = vn[1]; A.z = vn[2]; A.w = vn[3];
        B4.x = vn[4]; B4.y = vn[5]; B4.z = vn[6]; B4.w = s;
        float4* pp = (float4*)(sm.m.ps + ix * 8);
        pp[0] = A; pp[1] = B4;
      }

      int c0 = p0 + blo;               // global col of staged idx 0
      c0 %= NLON_O; if (c0 < 0) c0 += NLON_O;

      auto macRun = [&](float (&G)[7][5]) {
        const float* xr = sm.m.xu + il * XSTR + pbase;
        const float* ps = sm.m.ps;
        int b = 0;
        for (; b + 4 <= cnt; b += 4) {
          const float* xp = xr + b;
          float xw[8];
#pragma unroll
          for (int j = 0; j < 8; ++j) xw[j] = xp[j];
#pragma unroll
          for (int u = 0; u < 4; ++u) {
            const float4 pa = *(const float4*)(ps + (b + u) * 8);
            const float4 pb = *(const float4*)(ps + (b + u) * 8 + 4);
            if (pb.w != 0.0f) {
              KROW(G[0], pa.x, xw[u], xw[u + 1], xw[u + 2], xw[u + 3], xw[u + 4]);
              KROW(G[1], pa.y, xw[u], xw[u + 1], xw[u + 2], xw[u + 3], xw[u + 4]);
              KROW(G[2], pa.z, xw[u], xw[u + 1], xw[u + 2], xw[u + 3], xw[u + 4]);
              KROW(G[3], pa.w, xw[u], xw[u + 1], xw[u + 2], xw[u + 3], xw[u + 4]);
              KROW(G[4], pb.x, xw[u], xw[u + 1], xw[u + 2], xw[u + 3], xw[u + 4]);
              KROW(G[5], pb.y, xw[u], xw[u + 1], xw[u + 2], xw[u + 3], xw[u + 4]);
              KROW(G[6], pb.z, xw[u], xw[u + 1], xw[u + 2], xw[u + 3], xw[u + 4]);
            }
          }
        }
        for (; b < cnt; ++b) {
          const float* xp = xr + b;
          float x0 = xp[0], x1 = xp[1], x2 = xp[2], x3 = xp[3], x4 = xp[4];
          const float4 pa = *(const float4*)(ps + b * 8);
          const float4 pb = *(const float4*)(ps + b * 8 + 4);
          if (pb.w != 0.0f) {
            KROW(G[0], pa.x, x0, x1, x2, x3, x4);
            KROW(G[1], pa.y, x0, x1, x2, x3, x4);
            KROW(G[2], pa.z, x0, x1, x2, x3, x4);
            KROW(G[3], pa.w, x0, x1, x2, x3, x4);
            KROW(G[4], pb.x, x0, x1, x2, x3, x4);
            KROW(G[5], pb.y, x0, x1, x2, x3, x4);
            KROW(G[6], pb.z, x0, x1, x2, x3, x4);
          }
        }
      };

      for (int h = 0; h < 2; ++h) {
        // stage xu rows for this i-half
        for (int ir2 = 0; ir2 < 16; ++ir2) {
          const float* src = xu + (size_t)(h * 16 + ir2) * (NLAT_O * NLON_O) +
                             (size_t)tp * NLON_O;
          float* dst = sm.m.xu + ir2 * XSTR;
          for (int c = tid; c < W; c += 256) {
            int g = c0 + c;
            if (g >= NLON_O) g -= NLON_O;
            if (g >= NLON_O) g -= NLON_O;
            dst[c] = src[g];
          }
        }
        __syncthreads();
        if (h == 0) macRun(Ga); else macRun(Gb);
        __syncthreads();
      }
    }
  }

  // ---- GEMM phase: y[o,p] = sum_{i,k} w[o,i,k] * G[k,i,p] ----
  auto dumpG = [&](float (&G)[7][5]) {
#pragma unroll
    for (int k = 0; k < 7; ++k) {
#pragma unroll
      for (int j = 0; j < 5; ++j)
        sm.g[(k * 16 + il) * GSTR + pbase + j] = G[k][j];
    }
  };

  const int op2 = (tid >> 4) << 1;   // even o of the o-pair
  const int pc = tid & 15;
  const int pbase2 = 5 * pc;
  float ya[2][5] = {{0.0f}};

  for (int h = 0; h < 2; ++h) {
    if (h == 0) dumpG(Ga); else dumpG(Gb);
    __syncthreads();
#pragma unroll 1
    for (int ig = 0; ig < 16; ++ig) {
      const int iglob = h * 16 + ig;
      const float* wp0 = w + op2 * (CI_N * K_N) + iglob * K_N;
      const float* wp1 = wp0 + CI_N * K_N;
#pragma unroll
      for (int k = 0; k < 7; ++k) {
        float w0 = wp0[k], w1 = wp1[k];
        const float* gp = sm.g + (k * 16 + ig) * GSTR + pbase2;
#pragma unroll
        for (int j = 0; j < 5; ++j) {
          float gv = gp[j];
          ya[0][j] += w0 * gv;
          ya[1][j] += w1 * gv;
        }
      }
    }
    __syncthreads();
  }

#pragma unroll
  for (int oo = 0; oo < 2; ++oo) {
    float* yo = y + (size_t)(op2 + oo) * (NLAT_O * NLON_O) + (size_t)t * NLON_O +
                p0 + pbase2;
#pragma unroll
    for (int j = 0; j < 5; ++j) yo[j] = ya[oo][j];
  }
}

// ---------------- launch ----------------------------------------------------
extern "C" void kernel_launch(void* const* d_in, const int* in_sizes, int n_in,
                              void* d_out, int out_size, void* d_ws, size_t ws_size,
                              hipStream_t stream) {
  (void)in_sizes; (void)n_in; (void)out_size; (void)ws_size;
  const float* x = (const float*)d_in[0];
  const float* w = (const float*)d_in[1];
  float* y = (float*)d_out;

  float* xu = (float*)d_ws;                                   // 32*361*720 f32
  float* recip = xu + (size_t)CI_N * NLAT_O * NLON_O;         // 361*7 f32

  int n_up = CI_N * NLAT_O * NLON_O;
  upsample_kernel<<<(n_up + 255) / 256, 256, 0, stream>>>(x, xu);
  scale_kernel<<<NLAT_O, 256, 0, stream>>>(recip);

  dim3 grid(NLAT_O, NTILE);
  disco_kernel<<<grid, 256, 0, stream>>>(xu, recip, w, y);
}

// Round 2
// 4894.129 us; speedup vs baseline: 1.7287x; 1.7287x over previous
//
#include <hip/hip_runtime.h>
#include <math.h>

#define NLAT_I 240
#define NLON_I 480
#define NLAT_O 361
#define NLON_O 720
#define CI_N 32
#define CO_N 32
#define K_N 7
#define WOFF 10
#define WLAT 21

#define PI_F 3.14159265358979323846f
#define TWOPI_F 6.28318530717958647692f
#define DLAT_V (PI_F / 360.0f)
#define DPHI_V (TWOPI_F / 720.0f)
#define CUTOFF_V (3.25f * PI_F / 120.0f)
#define DR_V (CUTOFF_V / 3.0f)
#define IDR_V (1.0f / DR_V)
#define DPH_V (TWOPI_F / 3.0f)
#define IDPH_V (1.0f / DPH_V)
#define QF_V (DLAT_V * DPHI_V)

// tiling
#define PT 80          // lon columns per workgroup tile (9 * 80 = 720)
#define NTILE 9
#define CHB 96         // beta cols per unit
#define XW 176         // staged lon cols per unit (CHB + PT - 1 = 175, round to 176)
#define XSTR 177       // LDS row stride (odd vs 32 banks)
#define UPB 16         // units per item
#define GSTR 85
#define NBLOCKS 2048

// ---------------- psi evaluation --------------------------------------------
__device__ __forceinline__ void psi_eval(float ct, float st, float cg, float sg,
                                         float q, float bang, float v[7]) {
  float sb, cb;
  sincosf(bang, &sb, &cb);
  float dx = sg * cb - st;
  float dy = sg * sb;
  float dz = cg - ct;
  float c2 = dx * dx + dy * dy + dz * dz;
  float r = 2.0f * asinf(fminf(1.0f, 0.5f * sqrtf(c2)));
  if (r <= CUTOFF_V) {
    float xx = ct * cb * sg - st * cg;
    float yy = sb * sg;
    float phi = atan2f(yy, xx);
    if (phi < 0.0f) phi += TWOPI_F;
    v[0] = fmaxf(0.0f, 1.0f - r * IDR_V) * q;
#pragma unroll
    for (int k = 1; k < 7; ++k) {
      const float irdr = (float)(1 + (k - 1) / 3) * DR_V;
      const float ipph = (float)((k - 1) % 3) * DPH_V;
      float rad = fmaxf(0.0f, 1.0f - fabsf(r - irdr) * IDR_V);
      float dd = fabsf(phi - ipph);
      dd = fminf(dd, TWOPI_F - dd);
      float az = fmaxf(0.0f, 1.0f - dd * IDPH_V);
      v[k] = rad * az * q;
    }
  } else {
#pragma unroll
    for (int k = 0; k < 7; ++k) v[k] = 0.0f;
  }
}

// per-(t,d) lon window half-width: -1 empty, 360 full circle
__device__ __forceinline__ int windowB(int t, int d) {
  int tp = t + d - WOFF;
  if (tp < 0 || tp > NLAT_O - 1) return -1;
  float th = (float)t * DLAT_V, ga = (float)tp * DLAT_V;
  float st = sinf(th), ct = cosf(th), sg = sinf(ga), cg = cosf(ga);
  float den = st * sg;
  float num = cosf(CUTOFF_V) - ct * cg;
  if (den < 1e-9f) return (fabsf(th - ga) <= CUTOFF_V) ? 360 : -1;
  if (num >= den) return -1;
  if (num <= -den) return 360;
  int B = (int)ceilf(acosf(num / den) * (1.0f / DPHI_V)) + 1;  // +1 margin; psi masks
  return B > 360 ? 360 : B;
}

// ---------------- kernel 1: bilinear upsample (+queue counter reset) --------
__global__ void upsample_kernel(const float* __restrict__ x, float* __restrict__ xu,
                                int* __restrict__ counter) {
  if (blockIdx.x == 0 && threadIdx.x == 0) *counter = 0;
  int idx = blockIdx.x * 256 + threadIdx.x;
  if (idx >= CI_N * NLAT_O * NLON_O) return;
  int p = idx % NLON_O;
  int r = idx / NLON_O;
  int t = r % NLAT_O;
  int i = r / NLAT_O;

  double post = (double)t * (239.0 / 360.0);
  int i0 = (int)floor(post);
  if (i0 < 0) i0 = 0;
  if (i0 > NLAT_I - 1) i0 = NLAT_I - 1;
  int i1 = i0 + 1; if (i1 > NLAT_I - 1) i1 = NLAT_I - 1;
  float wt = (float)(post - (double)i0);

  double posp = (double)p * (2.0 / 3.0);
  double j0f = floor(posp);
  int j0 = ((int)j0f) % NLON_I;
  int j1 = (j0 + 1) % NLON_I;
  float wp = (float)(posp - j0f);

  const float* xi = x + (size_t)i * (NLAT_I * NLON_I);
  float a = xi[i0 * NLON_I + j0];
  float b = xi[i0 * NLON_I + j1];
  float c = xi[i1 * NLON_I + j0];
  float d = xi[i1 * NLON_I + j1];
  float l0 = (1.0f - wt) * a + wt * c;
  float l1 = (1.0f - wt) * b + wt * d;
  xu[idx] = (1.0f - wp) * l0 + wp * l1;
}

// ---------------- kernel 2: per-(k,t) normalization scales ------------------
__global__ void scale_kernel(float* __restrict__ recip) {
  int t = blockIdx.x;
  int tid = threadIdx.x;
  float th = (float)t * DLAT_V;
  float st, ct;
  sincosf(th, &st, &ct);
  float acc[7];
#pragma unroll
  for (int k = 0; k < 7; ++k) acc[k] = 0.0f;

  for (int d = 0; d < WLAT; ++d) {
    int tp = t + d - WOFF;
    if (tp < 0 || tp > NLAT_O - 1) continue;
    float ga = (float)tp * DLAT_V;
    float sg, cg;
    sincosf(ga, &sg, &cg);
    float q = sg * QF_V;
    for (int j = tid; j < NLON_O; j += 256) {
      float v[7];
      psi_eval(ct, st, cg, sg, q, (float)j * DPHI_V, v);
#pragma unroll
      for (int k = 0; k < 7; ++k) acc[k] += v[k];
    }
  }
#pragma unroll
  for (int k = 0; k < 7; ++k) {
    float a = acc[k];
    for (int off = 32; off > 0; off >>= 1) a += __shfl_down(a, off, 64);
    acc[k] = a;
  }
  __shared__ float red[4][7];
  int wid = tid >> 6;
  if ((tid & 63) == 0) {
#pragma unroll
    for (int k = 0; k < 7; ++k) red[wid][k] = acc[k];
  }
  __syncthreads();
  if (tid == 0) {
#pragma unroll
    for (int k = 0; k < 7; ++k) {
      float s = red[0][k] + red[1][k] + red[2][k] + red[3][k];
      recip[t * 7 + k] = 1.0f / fmaxf(s, 1e-8f);
    }
  }
}

// ---------------- kernel 3: persistent balanced conv + channel GEMM ---------
#define KROW(R, PK, X0, X1, X2, X3, X4)                                   \
  if ((PK) != 0.0f) {                                                     \
    R[0] += (PK) * (X0); R[1] += (PK) * (X1); R[2] += (PK) * (X2);        \
    R[3] += (PK) * (X3); R[4] += (PK) * (X4);                             \
  }

__global__ __launch_bounds__(256) void disco_kernel(
    const float* __restrict__ xu, const float* __restrict__ recip,
    const float* __restrict__ w, float* __restrict__ y,
    int* __restrict__ counter) {
  const int tid = threadIdx.x;

  __shared__ __align__(16) union SMem {
    struct {
      float xu[32 * XSTR];     // 32 i-rows staged for one unit
      float ps[CHB * 8];       // psi: [idx][k0..k6, any]
    } m;
    float g[7 * 16 * GSTR];    // G dump for GEMM phase
  } sm;
  __shared__ int Sbuf[362];    // exclusive prefix of S(j) over pole-first order
  __shared__ int Bd[WLAT];
  __shared__ int Ucum[WLAT + 1];
  __shared__ float rc[7];
  __shared__ int curItem;

  // ---- per-block schedule build (identical in every block => consistent) ----
  for (int j = tid; j < 361; j += 256) {
    int t = (j & 1) ? 360 - (j >> 1) : (j >> 1);   // poles first
    int U = 0;
    for (int d = 0; d < WLAT; ++d) {
      int B = windowB(t, d);
      if (B >= 0) {
        int wdt = (B >= 360) ? 720 : 2 * B + 1;
        U += (wdt + CHB - 1) / CHB;
      }
    }
    Sbuf[j] = NTILE * ((U + UPB - 1) / UPB);
  }
  __syncthreads();
  if (tid == 0) {
    int run = 0;
    for (int j = 0; j < 361; ++j) { int v = Sbuf[j]; Sbuf[j] = run; run += v; }
    Sbuf[361] = run;
  }
  __syncthreads();
  const int NTOT = Sbuf[361];

  const int il = tid & 15;     // i within half
  const int cl = tid >> 4;     // 0..15 -> 5-col chunk
  const int pbase = 5 * cl;

  while (true) {
    if (tid == 0) curItem = atomicAdd(counter, 1);
    __syncthreads();
    const int m = curItem;
    if (m >= NTOT) break;

    // locate item: j (t in pole-first order), tile, part
    int lo = 0, hi = 360;
    while (lo < hi) {
      int mid = (lo + hi + 1) >> 1;
      if (Sbuf[mid] <= m) lo = mid; else hi = mid - 1;
    }
    const int j = lo;
    const int r = m - Sbuf[j];
    const int t = (j & 1) ? 360 - (j >> 1) : (j >> 1);
    const int tile = r % NTILE;
    const int part = r / NTILE;
    const int p0 = tile * PT;

    if (tid < WLAT) Bd[tid] = windowB(t, tid);
    if (tid < 7) rc[tid] = recip[t * 7 + tid];
    __syncthreads();
    if (tid == 0) {
      int run = 0; Ucum[0] = 0;
      for (int d = 0; d < WLAT; ++d) {
        int B = Bd[d]; int u = 0;
        if (B >= 0) { int wdt = (B >= 360) ? 720 : 2 * B + 1; u = (wdt + CHB - 1) / CHB; }
        run += u; Ucum[d + 1] = run;
      }
    }
    __syncthreads();
    const int U = Ucum[WLAT];
    const int u0 = part * UPB;
    const int u1 = (u0 + UPB < U) ? u0 + UPB : U;

    float Ga[7][5] = {{0.0f}};
    float Gb[7][5] = {{0.0f}};
    float tht = (float)t * DLAT_V;
    float stv, ctv;
    sincosf(tht, &stv, &ctv);

    int dcur = 0;
    for (int u = u0; u < u1; ++u) {
      while (Ucum[dcur + 1] <= u) ++dcur;
      const int d = dcur;
      const int c = u - Ucum[d];
      const int B = Bd[d];
      const int wlo = -B;
      const int whi = (B >= 360) ? 359 : B;
      const int blo = wlo + c * CHB;
      int cnt = whi - blo + 1; if (cnt > CHB) cnt = CHB;
      const int tp = t + d - WOFF;
      float ga = (float)tp * DLAT_V;
      float sgv, cgv;
      sincosf(ga, &sgv, &cgv);
      float q = sgv * QF_V;

      // stage psi for this unit
      for (int ix = tid; ix < cnt; ix += 256) {
        int b = blo + ix;
        float v[7];
        psi_eval(ctv, stv, cgv, sgv, q, (float)b * DPHI_V, v);
        float s = 0.0f;
        float vn[7];
#pragma unroll
        for (int k = 0; k < 7; ++k) { vn[k] = v[k] * rc[k]; s += vn[k]; }
        float4 A, B4;
        A.x = vn[0]; A.y = vn[1]; A.z = vn[2]; A.w = vn[3];
        B4.x = vn[4]; B4.y = vn[5]; B4.z = vn[6]; B4.w = s;
        float4* pp = (float4*)(sm.m.ps + ix * 8);
        pp[0] = A; pp[1] = B4;
      }

      // stage xu: all 32 i-rows x XW cols
      int c0 = p0 + blo;
      c0 %= NLON_O; if (c0 < 0) c0 += NLON_O;
      const float* srcbase = xu + (size_t)tp * NLON_O;
      for (int c2 = tid; c2 < 32 * XW; c2 += 256) {
        int row = c2 / XW;
        int col = c2 - row * XW;
        int g = c0 + col; if (g >= NLON_O) g -= NLON_O;
        sm.m.xu[row * XSTR + col] = srcbase[(size_t)row * (NLAT_O * NLON_O) + g];
      }
      __syncthreads();

      // MAC over both halves
#pragma unroll 1
      for (int h = 0; h < 2; ++h) {
        const float* xr = sm.m.xu + (h * 16 + il) * XSTR + pbase;
        const float* ps = sm.m.ps;
        float (&G)[7][5] = h ? Gb : Ga;
        int b = 0;
        for (; b + 4 <= cnt; b += 4) {
          const float* xp = xr + b;
          float xw[8];
#pragma unroll
          for (int jj = 0; jj < 8; ++jj) xw[jj] = xp[jj];
#pragma unroll
          for (int uu = 0; uu < 4; ++uu) {
            const float4 pa = *(const float4*)(ps + (b + uu) * 8);
            const float4 pb = *(const float4*)(ps + (b + uu) * 8 + 4);
            if (pb.w != 0.0f) {
              KROW(G[0], pa.x, xw[uu], xw[uu + 1], xw[uu + 2], xw[uu + 3], xw[uu + 4]);
              KROW(G[1], pa.y, xw[uu], xw[uu + 1], xw[uu + 2], xw[uu + 3], xw[uu + 4]);
              KROW(G[2], pa.z, xw[uu], xw[uu + 1], xw[uu + 2], xw[uu + 3], xw[uu + 4]);
              KROW(G[3], pa.w, xw[uu], xw[uu + 1], xw[uu + 2], xw[uu + 3], xw[uu + 4]);
              KROW(G[4], pb.x, xw[uu], xw[uu + 1], xw[uu + 2], xw[uu + 3], xw[uu + 4]);
              KROW(G[5], pb.y, xw[uu], xw[uu + 1], xw[uu + 2], xw[uu + 3], xw[uu + 4]);
              KROW(G[6], pb.z, xw[uu], xw[uu + 1], xw[uu + 2], xw[uu + 3], xw[uu + 4]);
            }
          }
        }
        for (; b < cnt; ++b) {
          const float* xp = xr + b;
          float x0 = xp[0], x1 = xp[1], x2 = xp[2], x3 = xp[3], x4 = xp[4];
          const float4 pa = *(const float4*)(ps + b * 8);
          const float4 pb = *(const float4*)(ps + b * 8 + 4);
          if (pb.w != 0.0f) {
            KROW(G[0], pa.x, x0, x1, x2, x3, x4);
            KROW(G[1], pa.y, x0, x1, x2, x3, x4);
            KROW(G[2], pa.z, x0, x1, x2, x3, x4);
            KROW(G[3], pa.w, x0, x1, x2, x3, x4);
            KROW(G[4], pb.x, x0, x1, x2, x3, x4);
            KROW(G[5], pb.y, x0, x1, x2, x3, x4);
            KROW(G[6], pb.z, x0, x1, x2, x3, x4);
          }
        }
      }
      __syncthreads();
    }

    // ---- GEMM phase: y[o,p] += sum_{i,k} w[o,i,k] * G[k,i,p] ----
    const int op2 = (tid >> 4) << 1;
    const int pc = tid & 15;
    const int pbase2 = 5 * pc;
    float ya[2][5] = {{0.0f}};

#pragma unroll 1
    for (int h = 0; h < 2; ++h) {
      {
        float (&G)[7][5] = h ? Gb : Ga;
#pragma unroll
        for (int k = 0; k < 7; ++k)
#pragma unroll
          for (int jj = 0; jj < 5; ++jj)
            sm.g[(k * 16 + il) * GSTR + pbase + jj] = G[k][jj];
      }
      __syncthreads();
#pragma unroll 1
      for (int ig = 0; ig < 16; ++ig) {
        const int iglob = h * 16 + ig;
        const float* wp0 = w + op2 * (CI_N * K_N) + iglob * K_N;
        const float* wp1 = wp0 + CI_N * K_N;
#pragma unroll
        for (int k = 0; k < 7; ++k) {
          float w0 = wp0[k], w1 = wp1[k];
          const float* gp = sm.g + (k * 16 + ig) * GSTR + pbase2;
#pragma unroll
          for (int jj = 0; jj < 5; ++jj) {
            float gv = gp[jj];
            ya[0][jj] += w0 * gv;
            ya[1][jj] += w1 * gv;
          }
        }
      }
      __syncthreads();
    }

#pragma unroll
    for (int oo = 0; oo < 2; ++oo) {
      float* yo = y + (size_t)(op2 + oo) * (NLAT_O * NLON_O) + (size_t)t * NLON_O +
                  p0 + pbase2;
#pragma unroll
      for (int jj = 0; jj < 5; ++jj) atomicAdd(&yo[jj], ya[oo][jj]);
    }
  }
}

// ---------------- launch ----------------------------------------------------
extern "C" void kernel_launch(void* const* d_in, const int* in_sizes, int n_in,
                              void* d_out, int out_size, void* d_ws, size_t ws_size,
                              hipStream_t stream) {
  (void)in_sizes; (void)n_in; (void)out_size; (void)ws_size;
  const float* x = (const float*)d_in[0];
  const float* w = (const float*)d_in[1];
  float* y = (float*)d_out;

  float* xu = (float*)d_ws;                                   // 32*361*720 f32
  float* recip = xu + (size_t)CI_N * NLAT_O * NLON_O;         // 361*7 f32
  int* counter = (int*)(recip + NLAT_O * K_N);                // 1 int

  hipMemsetAsync(y, 0, (size_t)CO_N * NLAT_O * NLON_O * sizeof(float), stream);

  int n_up = CI_N * NLAT_O * NLON_O;
  upsample_kernel<<<(n_up + 255) / 256, 256, 0, stream>>>(x, xu, counter);
  scale_kernel<<<NLAT_O, 256, 0, stream>>>(recip);

  disco_kernel<<<NBLOCKS, 256, 0, stream>>>(xu, recip, w, y, counter);
}

// Round 3
// 2040.248 us; speedup vs baseline: 4.1468x; 2.3988x over previous
//
#include <hip/hip_runtime.h>
#include <math.h>

#define NLAT_I 240
#define NLON_I 480
#define NLAT_O 361
#define NLON_O 720
#define CI_N 32
#define CO_N 32
#define K_N 7
#define WOFF 10
#define WLAT 21

#define PI_F 3.14159265358979323846f
#define TWOPI_F 6.28318530717958647692f
#define DLAT_V (PI_F / 360.0f)
#define DPHI_V (TWOPI_F / 720.0f)
#define CUTOFF_V (3.25f * PI_F / 120.0f)
#define DR_V (CUTOFF_V / 3.0f)
#define IDR_V (1.0f / DR_V)
#define DPH_V (TWOPI_F / 3.0f)
#define IDPH_V (1.0f / DPH_V)
#define QF_V (DLAT_V * DPHI_V)

// tiling
#define PT 80          // lon columns per workgroup tile (9 * 80 = 720)
#define NTILE 9
#define CHB 96         // max beta cols per unit
#define XW 176         // max staged lon cols (CHB + PT - 1 = 175, +1)
#define XSTR 177       // LDS row stride
#define UPB 16         // units per item
#define GSTR 85
#define NBLOCKS 2048

// ---------------- psi evaluation --------------------------------------------
__device__ __forceinline__ void psi_eval(float ct, float st, float cg, float sg,
                                         float q, float bang, float v[7]) {
  float sb, cb;
  sincosf(bang, &sb, &cb);
  float dx = sg * cb - st;
  float dy = sg * sb;
  float dz = cg - ct;
  float c2 = dx * dx + dy * dy + dz * dz;
  float r = 2.0f * asinf(fminf(1.0f, 0.5f * sqrtf(c2)));
  if (r <= CUTOFF_V) {
    float xx = ct * cb * sg - st * cg;
    float yy = sb * sg;
    float phi = atan2f(yy, xx);
    if (phi < 0.0f) phi += TWOPI_F;
    v[0] = fmaxf(0.0f, 1.0f - r * IDR_V) * q;
#pragma unroll
    for (int k = 1; k < 7; ++k) {
      const float irdr = (float)(1 + (k - 1) / 3) * DR_V;
      const float ipph = (float)((k - 1) % 3) * DPH_V;
      float rad = fmaxf(0.0f, 1.0f - fabsf(r - irdr) * IDR_V);
      float dd = fabsf(phi - ipph);
      dd = fminf(dd, TWOPI_F - dd);
      float az = fmaxf(0.0f, 1.0f - dd * IDPH_V);
      v[k] = rad * az * q;
    }
  } else {
#pragma unroll
    for (int k = 0; k < 7; ++k) v[k] = 0.0f;
  }
}

// per-(t,d) lon window half-width: -1 empty, 360 full circle
__device__ __forceinline__ int windowB(int t, int d) {
  int tp = t + d - WOFF;
  if (tp < 0 || tp > NLAT_O - 1) return -1;
  float th = (float)t * DLAT_V, ga = (float)tp * DLAT_V;
  float st = sinf(th), ct = cosf(th), sg = sinf(ga), cg = cosf(ga);
  float den = st * sg;
  float num = cosf(CUTOFF_V) - ct * cg;
  if (den < 1e-9f) return (fabsf(th - ga) <= CUTOFF_V) ? 360 : -1;
  if (num >= den) return -1;
  if (num <= -den) return 360;
  int B = (int)ceilf(acosf(num / den) * (1.0f / DPHI_V)) + 1;  // +1 margin; psi masks
  return B > 360 ? 360 : B;
}

// ---------------- kernel 1: bilinear upsample (+queue counter reset) --------
__global__ void upsample_kernel(const float* __restrict__ x, float* __restrict__ xu,
                                int* __restrict__ counter) {
  if (blockIdx.x == 0 && threadIdx.x == 0) *counter = 0;
  int idx = blockIdx.x * 256 + threadIdx.x;
  if (idx >= CI_N * NLAT_O * NLON_O) return;
  int p = idx % NLON_O;
  int r = idx / NLON_O;
  int t = r % NLAT_O;
  int i = r / NLAT_O;

  double post = (double)t * (239.0 / 360.0);
  int i0 = (int)floor(post);
  if (i0 < 0) i0 = 0;
  if (i0 > NLAT_I - 1) i0 = NLAT_I - 1;
  int i1 = i0 + 1; if (i1 > NLAT_I - 1) i1 = NLAT_I - 1;
  float wt = (float)(post - (double)i0);

  double posp = (double)p * (2.0 / 3.0);
  double j0f = floor(posp);
  int j0 = ((int)j0f) % NLON_I;
  int j1 = (j0 + 1) % NLON_I;
  float wp = (float)(posp - j0f);

  const float* xi = x + (size_t)i * (NLAT_I * NLON_I);
  float a = xi[i0 * NLON_I + j0];
  float b = xi[i0 * NLON_I + j1];
  float c = xi[i1 * NLON_I + j0];
  float d = xi[i1 * NLON_I + j1];
  float l0 = (1.0f - wt) * a + wt * c;
  float l1 = (1.0f - wt) * b + wt * d;
  xu[idx] = (1.0f - wp) * l0 + wp * l1;
}

// ---------------- kernel 2: per-(k,t) normalization scales ------------------
__global__ void scale_kernel(float* __restrict__ recip) {
  int t = blockIdx.x;
  int tid = threadIdx.x;
  float th = (float)t * DLAT_V;
  float st, ct;
  sincosf(th, &st, &ct);
  float acc[7];
#pragma unroll
  for (int k = 0; k < 7; ++k) acc[k] = 0.0f;

  for (int d = 0; d < WLAT; ++d) {
    int tp = t + d - WOFF;
    if (tp < 0 || tp > NLAT_O - 1) continue;
    float ga = (float)tp * DLAT_V;
    float sg, cg;
    sincosf(ga, &sg, &cg);
    float q = sg * QF_V;
    for (int j = tid; j < NLON_O; j += 256) {
      float v[7];
      psi_eval(ct, st, cg, sg, q, (float)j * DPHI_V, v);
#pragma unroll
      for (int k = 0; k < 7; ++k) acc[k] += v[k];
    }
  }
#pragma unroll
  for (int k = 0; k < 7; ++k) {
    float a = acc[k];
    for (int off = 32; off > 0; off >>= 1) a += __shfl_down(a, off, 64);
    acc[k] = a;
  }
  __shared__ float red[4][7];
  int wid = tid >> 6;
  if ((tid & 63) == 0) {
#pragma unroll
    for (int k = 0; k < 7; ++k) red[wid][k] = acc[k];
  }
  __syncthreads();
  if (tid == 0) {
#pragma unroll
    for (int k = 0; k < 7; ++k) {
      float s = red[0][k] + red[1][k] + red[2][k] + red[3][k];
      recip[t * 7 + k] = 1.0f / fmaxf(s, 1e-8f);
    }
  }
}

// ---------------- kernel 3: persistent balanced conv + channel GEMM ---------
// Unconditional 5-FMA row (psi value is wave-uniform; zero-psi FMAs are cheaper
// than per-row compare+branch)
#define KROW(R, PK, X0, X1, X2, X3, X4)                                   \
  { R[0] += (PK) * (X0); R[1] += (PK) * (X1); R[2] += (PK) * (X2);        \
    R[3] += (PK) * (X3); R[4] += (PK) * (X4); }

__global__ __launch_bounds__(256) void disco_kernel(
    const float* __restrict__ xu, const float* __restrict__ recip,
    const float* __restrict__ w, float* __restrict__ y,
    int* __restrict__ counter) {
  const int tid = threadIdx.x;

  __shared__ __align__(16) union SMem {
    struct {
      float xu[32 * XSTR];     // 32 i-rows staged for one unit
      float ps[CHB * 8];       // psi: [idx][k0..k6, any]
    } m;
    float g[7 * 16 * GSTR];    // G dump for GEMM phase
  } sm;
  __shared__ int Sbuf[362];    // exclusive prefix of items over pole-first order
  __shared__ int Bd[WLAT];
  __shared__ int Ucum[WLAT + 1];
  __shared__ float rc[7];
  __shared__ int curItem;

  // ---- per-block schedule build (identical in every block => consistent) ----
  for (int j = tid; j < 361; j += 256) {
    int t = (j & 1) ? 360 - (j >> 1) : (j >> 1);   // poles first
    int U = 0;
    for (int d = 0; d < WLAT; ++d) {
      int B = windowB(t, d);
      if (B >= 0) {
        int wdt = (B >= 360) ? 720 : 2 * B + 1;
        U += (wdt + CHB - 1) / CHB;
      }
    }
    Sbuf[j] = NTILE * ((U + UPB - 1) / UPB);
  }
  __syncthreads();
  if (tid == 0) {
    int run = 0;
    for (int j = 0; j < 361; ++j) { int v = Sbuf[j]; Sbuf[j] = run; run += v; }
    Sbuf[361] = run;
  }
  __syncthreads();
  const int NTOT = Sbuf[361];

  const int il = tid & 15;     // i within half
  const int cl = tid >> 4;     // 0..15 -> 5-col chunk
  const int pbase = 5 * cl;
  const int srow = tid >> 3;   // staging: row 0..31
  const int scol = tid & 7;    // staging: col start, step 8

  while (true) {
    if (tid == 0) curItem = atomicAdd(counter, 1);
    __syncthreads();
    const int m = curItem;
    if (m >= NTOT) break;

    // locate item: j (t in pole-first order), tile, part
    int lo = 0, hi = 360;
    while (lo < hi) {
      int mid = (lo + hi + 1) >> 1;
      if (Sbuf[mid] <= m) lo = mid; else hi = mid - 1;
    }
    const int j = lo;
    const int r = m - Sbuf[j];
    const int t = (j & 1) ? 360 - (j >> 1) : (j >> 1);
    const int tile = r % NTILE;
    const int part = r / NTILE;
    const int p0 = tile * PT;

    if (tid < WLAT) Bd[tid] = windowB(t, tid);
    if (tid < 7) rc[tid] = recip[t * 7 + tid];
    __syncthreads();
    if (tid == 0) {
      int run = 0; Ucum[0] = 0;
      for (int d = 0; d < WLAT; ++d) {
        int B = Bd[d]; int u = 0;
        if (B >= 0) { int wdt = (B >= 360) ? 720 : 2 * B + 1; u = (wdt + CHB - 1) / CHB; }
        run += u; Ucum[d + 1] = run;
      }
    }
    __syncthreads();
    const int U = Ucum[WLAT];
    const int u0 = part * UPB;
    const int u1 = (u0 + UPB < U) ? u0 + UPB : U;

    float Ga[7][5] = {{0.0f}};
    float Gb[7][5] = {{0.0f}};
    float tht = (float)t * DLAT_V;
    float stv, ctv;
    sincosf(tht, &stv, &ctv);

    // MAC over one staged unit for one i-half; statically bound G -> registers
    auto macRun = [&](float (&G)[7][5], int hbase, int cnt) {
      const float* xr = sm.m.xu + (hbase + il) * XSTR + pbase;
      const float* ps = sm.m.ps;
      int b = 0;
      for (; b + 4 <= cnt; b += 4) {
        const float* xp = xr + b;
        float xw[8];
#pragma unroll
        for (int jj = 0; jj < 8; ++jj) xw[jj] = xp[jj];
#pragma unroll
        for (int uu = 0; uu < 4; ++uu) {
          const float4 pa = *(const float4*)(ps + (b + uu) * 8);
          const float4 pb = *(const float4*)(ps + (b + uu) * 8 + 4);
          if (__builtin_amdgcn_readfirstlane(__float_as_uint(pb.w)) != 0u) {
            KROW(G[0], pa.x, xw[uu], xw[uu + 1], xw[uu + 2], xw[uu + 3], xw[uu + 4]);
            KROW(G[1], pa.y, xw[uu], xw[uu + 1], xw[uu + 2], xw[uu + 3], xw[uu + 4]);
            KROW(G[2], pa.z, xw[uu], xw[uu + 1], xw[uu + 2], xw[uu + 3], xw[uu + 4]);
            KROW(G[3], pa.w, xw[uu], xw[uu + 1], xw[uu + 2], xw[uu + 3], xw[uu + 4]);
            KROW(G[4], pb.x, xw[uu], xw[uu + 1], xw[uu + 2], xw[uu + 3], xw[uu + 4]);
            KROW(G[5], pb.y, xw[uu], xw[uu + 1], xw[uu + 2], xw[uu + 3], xw[uu + 4]);
            KROW(G[6], pb.z, xw[uu], xw[uu + 1], xw[uu + 2], xw[uu + 3], xw[uu + 4]);
          }
        }
      }
      for (; b < cnt; ++b) {
        const float* xp = xr + b;
        float x0 = xp[0], x1 = xp[1], x2 = xp[2], x3 = xp[3], x4 = xp[4];
        const float4 pa = *(const float4*)(ps + b * 8);
        const float4 pb = *(const float4*)(ps + b * 8 + 4);
        if (__builtin_amdgcn_readfirstlane(__float_as_uint(pb.w)) != 0u) {
          KROW(G[0], pa.x, x0, x1, x2, x3, x4);
          KROW(G[1], pa.y, x0, x1, x2, x3, x4);
          KROW(G[2], pa.z, x0, x1, x2, x3, x4);
          KROW(G[3], pa.w, x0, x1, x2, x3, x4);
          KROW(G[4], pb.x, x0, x1, x2, x3, x4);
          KROW(G[5], pb.y, x0, x1, x2, x3, x4);
          KROW(G[6], pb.z, x0, x1, x2, x3, x4);
        }
      }
    };

    int dcur = 0;
    for (int u = u0; u < u1; ++u) {
      while (Ucum[dcur + 1] <= u) ++dcur;
      const int d = dcur;
      const int c = u - Ucum[d];
      const int B = Bd[d];
      const int wlo = -B;
      const int whi = (B >= 360) ? 359 : B;
      const int blo = wlo + c * CHB;
      int cnt = whi - blo + 1; if (cnt > CHB) cnt = CHB;
      const int tp = t + d - WOFF;
      float ga = (float)tp * DLAT_V;
      float sgv, cgv;
      sincosf(ga, &sgv, &cgv);
      float q = sgv * QF_V;

      // stage psi for this unit
      for (int ix = tid; ix < cnt; ix += 256) {
        int b = blo + ix;
        float v[7];
        psi_eval(ctv, stv, cgv, sgv, q, (float)b * DPHI_V, v);
        float s = 0.0f;
        float vn[7];
#pragma unroll
        for (int k = 0; k < 7; ++k) { vn[k] = v[k] * rc[k]; s += vn[k]; }
        float4 A, B4;
        A.x = vn[0]; A.y = vn[1]; A.z = vn[2]; A.w = vn[3];
        B4.x = vn[4]; B4.y = vn[5]; B4.z = vn[6]; B4.w = s;
        float4* pp = (float4*)(sm.m.ps + ix * 8);
        pp[0] = A; pp[1] = B4;
      }

      // stage xu: 32 i-rows x W cols (only what this unit needs)
      const int W = cnt + PT - 1;
      int c0 = p0 + blo;
      c0 %= NLON_O; if (c0 < 0) c0 += NLON_O;
      {
        const float* srcrow = xu + (size_t)srow * (NLAT_O * NLON_O) +
                              (size_t)tp * NLON_O;
        float* dstrow = sm.m.xu + srow * XSTR;
        for (int col = scol; col < W; col += 8) {
          int g = c0 + col; if (g >= NLON_O) g -= NLON_O;
          dstrow[col] = srcrow[g];
        }
      }
      __syncthreads();

      macRun(Ga, 0, cnt);
      macRun(Gb, 16, cnt);
      __syncthreads();
    }

    // ---- GEMM phase: y[o,p] += sum_{i,k} w[o,i,k] * G[k,i,p] ----
    const int op2 = (tid >> 4) << 1;
    const int pc = tid & 15;
    const int pbase2 = 5 * pc;
    float ya[2][5] = {{0.0f}};

    auto gemmHalf = [&](float (&G)[7][5], int hbase) {
#pragma unroll
      for (int k = 0; k < 7; ++k)
#pragma unroll
        for (int jj = 0; jj < 5; ++jj)
          sm.g[(k * 16 + il) * GSTR + pbase + jj] = G[k][jj];
      __syncthreads();
#pragma unroll 1
      for (int ig = 0; ig < 16; ++ig) {
        const float* wp0 = w + op2 * (CI_N * K_N) + (hbase + ig) * K_N;
        const float* wp1 = wp0 + CI_N * K_N;
#pragma unroll
        for (int k = 0; k < 7; ++k) {
          float w0 = wp0[k], w1 = wp1[k];
          const float* gp = sm.g + (k * 16 + ig) * GSTR + pbase2;
#pragma unroll
          for (int jj = 0; jj < 5; ++jj) {
            float gv = gp[jj];
            ya[0][jj] += w0 * gv;
            ya[1][jj] += w1 * gv;
          }
        }
      }
      __syncthreads();
    };
    gemmHalf(Ga, 0);
    gemmHalf(Gb, 16);

#pragma unroll
    for (int oo = 0; oo < 2; ++oo) {
      float* yo = y + (size_t)(op2 + oo) * (NLAT_O * NLON_O) + (size_t)t * NLON_O +
                  p0 + pbase2;
#pragma unroll
      for (int jj = 0; jj < 5; ++jj) atomicAdd(&yo[jj], ya[oo][jj]);
    }
  }
}

// ---------------- launch ----------------------------------------------------
extern "C" void kernel_launch(void* const* d_in, const int* in_sizes, int n_in,
                              void* d_out, int out_size, void* d_ws, size_t ws_size,
                              hipStream_t stream) {
  (void)in_sizes; (void)n_in; (void)out_size; (void)ws_size;
  const float* x = (const float*)d_in[0];
  const float* w = (const float*)d_in[1];
  float* y = (float*)d_out;

  float* xu = (float*)d_ws;                                   // 32*361*720 f32
  float* recip = xu + (size_t)CI_N * NLAT_O * NLON_O;         // 361*7 f32
  int* counter = (int*)(recip + NLAT_O * K_N);                // 1 int

  hipMemsetAsync(y, 0, (size_t)CO_N * NLAT_O * NLON_O * sizeof(float), stream);

  int n_up = CI_N * NLAT_O * NLON_O;
  upsample_kernel<<<(n_up + 255) / 256, 256, 0, stream>>>(x, xu, counter);
  scale_kernel<<<NLAT_O, 256, 0, stream>>>(recip);

  disco_kernel<<<NBLOCKS, 256, 0, stream>>>(xu, recip, w, y, counter);
}

// Round 4
// 1935.654 us; speedup vs baseline: 4.3709x; 1.0540x over previous
//
#include <hip/hip_runtime.h>
#include <math.h>

#define NLAT_I 240
#define NLON_I 480
#define NLAT_O 361
#define NLON_O 720
#define XUW 896        // padded xu row width: cols [720,896) replicate [0,176)
#define CI_N 32
#define CO_N 32
#define K_N 7
#define WOFF 10
#define WLAT 21

#define PI_F 3.14159265358979323846f
#define TWOPI_F 6.28318530717958647692f
#define DLAT_V (PI_F / 360.0f)
#define DPHI_V (TWOPI_F / 720.0f)
#define CUTOFF_V (3.25f * PI_F / 120.0f)
#define DR_V (CUTOFF_V / 3.0f)
#define IDR_V (1.0f / DR_V)
#define DPH_V (TWOPI_F / 3.0f)
#define IDPH_V (1.0f / DPH_V)
#define QF_V (DLAT_V * DPHI_V)

// tiling
#define PT 80          // lon columns per workgroup tile (9 * 80 = 720)
#define NTILE 9
#define CHB 96         // max beta cols per unit
#define XSTR 180       // LDS row stride (mult of 4 -> 16B aligned rows)
#define UPB 16         // units per item
#define GSTR 85
#define NBLOCKS 2048

// ---------------- psi evaluation --------------------------------------------
__device__ __forceinline__ void psi_eval(float ct, float st, float cg, float sg,
                                         float q, float bang, float v[7]) {
  float sb, cb;
  sincosf(bang, &sb, &cb);
  float dx = sg * cb - st;
  float dy = sg * sb;
  float dz = cg - ct;
  float c2 = dx * dx + dy * dy + dz * dz;
  float r = 2.0f * asinf(fminf(1.0f, 0.5f * sqrtf(c2)));
  if (r <= CUTOFF_V) {
    float xx = ct * cb * sg - st * cg;
    float yy = sb * sg;
    float phi = atan2f(yy, xx);
    if (phi < 0.0f) phi += TWOPI_F;
    v[0] = fmaxf(0.0f, 1.0f - r * IDR_V) * q;
#pragma unroll
    for (int k = 1; k < 7; ++k) {
      const float irdr = (float)(1 + (k - 1) / 3) * DR_V;
      const float ipph = (float)((k - 1) % 3) * DPH_V;
      float rad = fmaxf(0.0f, 1.0f - fabsf(r - irdr) * IDR_V);
      float dd = fabsf(phi - ipph);
      dd = fminf(dd, TWOPI_F - dd);
      float az = fmaxf(0.0f, 1.0f - dd * IDPH_V);
      v[k] = rad * az * q;
    }
  } else {
#pragma unroll
    for (int k = 0; k < 7; ++k) v[k] = 0.0f;
  }
}

// per-(t,d) lon window half-width: -1 empty, 360 full circle
__device__ __forceinline__ int windowB(int t, int d) {
  int tp = t + d - WOFF;
  if (tp < 0 || tp > NLAT_O - 1) return -1;
  float th = (float)t * DLAT_V, ga = (float)tp * DLAT_V;
  float st = sinf(th), ct = cosf(th), sg = sinf(ga), cg = cosf(ga);
  float den = st * sg;
  float num = cosf(CUTOFF_V) - ct * cg;
  if (den < 1e-9f) return (fabsf(th - ga) <= CUTOFF_V) ? 360 : -1;
  if (num >= den) return -1;
  if (num <= -den) return 360;
  int B = (int)ceilf(acosf(num / den) * (1.0f / DPHI_V)) + 1;  // +1 margin; psi masks
  return B > 360 ? 360 : B;
}

// ---------------- kernel 1: bilinear upsample into padded layout ------------
__global__ void upsample_kernel(const float* __restrict__ x, float* __restrict__ xu,
                                int* __restrict__ counter) {
  if (blockIdx.x == 0 && threadIdx.x == 0) *counter = 0;
  int idx = blockIdx.x * 256 + threadIdx.x;
  if (idx >= CI_N * NLAT_O * XUW) return;
  int c = idx % XUW;
  int r = idx / XUW;
  int t = r % NLAT_O;
  int i = r / NLAT_O;
  int p = (c < NLON_O) ? c : c - NLON_O;   // wrap pad

  double post = (double)t * (239.0 / 360.0);
  int i0 = (int)floor(post);
  if (i0 < 0) i0 = 0;
  if (i0 > NLAT_I - 1) i0 = NLAT_I - 1;
  int i1 = i0 + 1; if (i1 > NLAT_I - 1) i1 = NLAT_I - 1;
  float wt = (float)(post - (double)i0);

  double posp = (double)p * (2.0 / 3.0);
  double j0f = floor(posp);
  int j0 = ((int)j0f) % NLON_I;
  int j1 = (j0 + 1) % NLON_I;
  float wp = (float)(posp - j0f);

  const float* xi = x + (size_t)i * (NLAT_I * NLON_I);
  float a = xi[i0 * NLON_I + j0];
  float b = xi[i0 * NLON_I + j1];
  float cc = xi[i1 * NLON_I + j0];
  float d = xi[i1 * NLON_I + j1];
  float l0 = (1.0f - wt) * a + wt * cc;
  float l1 = (1.0f - wt) * b + wt * d;
  xu[idx] = (1.0f - wp) * l0 + wp * l1;
}

// ---------------- kernel 2: per-(k,t) normalization scales ------------------
__global__ void scale_kernel(float* __restrict__ recip) {
  int t = blockIdx.x;
  int tid = threadIdx.x;
  float th = (float)t * DLAT_V;
  float st, ct;
  sincosf(th, &st, &ct);
  float acc[7];
#pragma unroll
  for (int k = 0; k < 7; ++k) acc[k] = 0.0f;

  for (int d = 0; d < WLAT; ++d) {
    int tp = t + d - WOFF;
    if (tp < 0 || tp > NLAT_O - 1) continue;
    float ga = (float)tp * DLAT_V;
    float sg, cg;
    sincosf(ga, &sg, &cg);
    float q = sg * QF_V;
    for (int j = tid; j < NLON_O; j += 256) {
      float v[7];
      psi_eval(ct, st, cg, sg, q, (float)j * DPHI_V, v);
#pragma unroll
      for (int k = 0; k < 7; ++k) acc[k] += v[k];
    }
  }
#pragma unroll
  for (int k = 0; k < 7; ++k) {
    float a = acc[k];
    for (int off = 32; off > 0; off >>= 1) a += __shfl_down(a, off, 64);
    acc[k] = a;
  }
  __shared__ float red[4][7];
  int wid = tid >> 6;
  if ((tid & 63) == 0) {
#pragma unroll
    for (int k = 0; k < 7; ++k) red[wid][k] = acc[k];
  }
  __syncthreads();
  if (tid == 0) {
#pragma unroll
    for (int k = 0; k < 7; ++k) {
      float s = red[0][k] + red[1][k] + red[2][k] + red[3][k];
      recip[t * 7 + k] = 1.0f / fmaxf(s, 1e-8f);
    }
  }
}

// ---------------- kernel 3: persistent balanced conv + channel GEMM ---------
#define KROW(R, PK, X0, X1, X2, X3, X4)                                   \
  { R[0] += (PK) * (X0); R[1] += (PK) * (X1); R[2] += (PK) * (X2);        \
    R[3] += (PK) * (X3); R[4] += (PK) * (X4); }

__global__ __launch_bounds__(256) void disco_kernel(
    const float* __restrict__ xu, const float* __restrict__ recip,
    const float* __restrict__ w, float* __restrict__ y,
    int* __restrict__ counter) {
  const int tid = threadIdx.x;

  __shared__ __align__(16) union SMem {
    struct {
      float xu[32 * XSTR];     // 32 i-rows staged for one unit
      float ps[CHB * 8];       // psi: [idx][k0..k6, any]
    } m;
    float g[7 * 16 * GSTR];    // G dump for GEMM phase
  } sm;
  __shared__ int Sbuf[362];    // exclusive prefix of items over pole-first order
  __shared__ int Bd[WLAT];
  __shared__ int Ucum[WLAT + 1];
  __shared__ float rc[7];
  __shared__ int curItem;

  // ---- per-block schedule build (identical in every block => consistent) ----
  for (int j = tid; j < 361; j += 256) {
    int t = (j & 1) ? 360 - (j >> 1) : (j >> 1);   // poles first
    int U = 0;
    for (int d = 0; d < WLAT; ++d) {
      int B = windowB(t, d);
      if (B >= 0) {
        int wdt = (B >= 360) ? 720 : 2 * B + 1;
        U += (wdt + CHB - 1) / CHB;
      }
    }
    Sbuf[j] = NTILE * ((U + UPB - 1) / UPB);
  }
  __syncthreads();
  if (tid == 0) {
    int run = 0;
    for (int j = 0; j < 361; ++j) { int v = Sbuf[j]; Sbuf[j] = run; run += v; }
    Sbuf[361] = run;
  }
  __syncthreads();
  const int NTOT = Sbuf[361];

  const int il = tid & 15;     // i within half
  const int cl = tid >> 4;     // 0..15 -> 5-col chunk
  const int pbase = 5 * cl;
  const int srow = tid >> 3;   // staging: row 0..31
  const int scol = tid & 7;    // staging: vec-col start, step 8

  while (true) {
    if (tid == 0) curItem = atomicAdd(counter, 1);
    __syncthreads();
    const int m = curItem;
    if (m >= NTOT) break;

    // locate item: j (t in pole-first order), tile, part
    int lo = 0, hi = 360;
    while (lo < hi) {
      int mid = (lo + hi + 1) >> 1;
      if (Sbuf[mid] <= m) lo = mid; else hi = mid - 1;
    }
    const int j = lo;
    const int r = m - Sbuf[j];
    const int t = (j & 1) ? 360 - (j >> 1) : (j >> 1);
    const int tile = r % NTILE;
    const int part = r / NTILE;
    const int p0 = tile * PT;

    if (tid < WLAT) Bd[tid] = windowB(t, tid);
    if (tid < 7) rc[tid] = recip[t * 7 + tid];
    __syncthreads();
    if (tid == 0) {
      int run = 0; Ucum[0] = 0;
      for (int d = 0; d < WLAT; ++d) {
        int B = Bd[d]; int u = 0;
        if (B >= 0) { int wdt = (B >= 360) ? 720 : 2 * B + 1; u = (wdt + CHB - 1) / CHB; }
        run += u; Ucum[d + 1] = run;
      }
    }
    __syncthreads();
    const int U = Ucum[WLAT];
    const int u0 = part * UPB;
    const int u1 = (u0 + UPB < U) ? u0 + UPB : U;

    float Ga[7][5] = {{0.0f}};
    float Gb[7][5] = {{0.0f}};
    float tht = (float)t * DLAT_V;
    float stv, ctv;
    sincosf(tht, &stv, &ctv);

    // MAC over one staged unit for one i-half; statically bound G -> registers
    auto macRun = [&](float (&G)[7][5], int hbase, int cnt, int off) {
      const float* xr = sm.m.xu + (hbase + il) * XSTR + off + pbase;
      const float* ps = sm.m.ps;
      int b = 0;
      for (; b + 4 <= cnt; b += 4) {
        const float* xp = xr + b;
        float xw[8];
#pragma unroll
        for (int jj = 0; jj < 8; ++jj) xw[jj] = xp[jj];
#pragma unroll
        for (int uu = 0; uu < 4; ++uu) {
          const float4 pa = *(const float4*)(ps + (b + uu) * 8);
          const float4 pb = *(const float4*)(ps + (b + uu) * 8 + 4);
          if (__builtin_amdgcn_readfirstlane(__float_as_uint(pb.w)) != 0u) {
            KROW(G[0], pa.x, xw[uu], xw[uu + 1], xw[uu + 2], xw[uu + 3], xw[uu + 4]);
            KROW(G[1], pa.y, xw[uu], xw[uu + 1], xw[uu + 2], xw[uu + 3], xw[uu + 4]);
            KROW(G[2], pa.z, xw[uu], xw[uu + 1], xw[uu + 2], xw[uu + 3], xw[uu + 4]);
            KROW(G[3], pa.w, xw[uu], xw[uu + 1], xw[uu + 2], xw[uu + 3], xw[uu + 4]);
            KROW(G[4], pb.x, xw[uu], xw[uu + 1], xw[uu + 2], xw[uu + 3], xw[uu + 4]);
            KROW(G[5], pb.y, xw[uu], xw[uu + 1], xw[uu + 2], xw[uu + 3], xw[uu + 4]);
            KROW(G[6], pb.z, xw[uu], xw[uu + 1], xw[uu + 2], xw[uu + 3], xw[uu + 4]);
          }
        }
      }
      for (; b < cnt; ++b) {
        const float* xp = xr + b;
        float x0 = xp[0], x1 = xp[1], x2 = xp[2], x3 = xp[3], x4 = xp[4];
        const float4 pa = *(const float4*)(ps + b * 8);
        const float4 pb = *(const float4*)(ps + b * 8 + 4);
        if (__builtin_amdgcn_readfirstlane(__float_as_uint(pb.w)) != 0u) {
          KROW(G[0], pa.x, x0, x1, x2, x3, x4);
          KROW(G[1], pa.y, x0, x1, x2, x3, x4);
          KROW(G[2], pa.z, x0, x1, x2, x3, x4);
          KROW(G[3], pa.w, x0, x1, x2, x3, x4);
          KROW(G[4], pb.x, x0, x1, x2, x3, x4);
          KROW(G[5], pb.y, x0, x1, x2, x3, x4);
          KROW(G[6], pb.z, x0, x1, x2, x3, x4);
        }
      }
    };

    int dcur = 0;
    for (int u = u0; u < u1; ++u) {
      while (Ucum[dcur + 1] <= u) ++dcur;
      const int d = dcur;
      const int c = u - Ucum[d];
      const int B = Bd[d];
      const int wlo = -B;
      const int whi = (B >= 360) ? 359 : B;
      const int blo = wlo + c * CHB;
      int cnt = whi - blo + 1; if (cnt > CHB) cnt = CHB;
      const int tp = t + d - WOFF;
      float ga = (float)tp * DLAT_V;
      float sgv, cgv;
      sincosf(ga, &sgv, &cgv);
      float q = sgv * QF_V;

      // stage psi for this unit
      for (int ix = tid; ix < cnt; ix += 256) {
        int b = blo + ix;
        float v[7];
        psi_eval(ctv, stv, cgv, sgv, q, (float)b * DPHI_V, v);
        float s = 0.0f;
        float vn[7];
#pragma unroll
        for (int k = 0; k < 7; ++k) { vn[k] = v[k] * rc[k]; s += vn[k]; }
        float4 A, B4;
        A.x = vn[0]; A.y = vn[1]; A.z = vn[2]; A.w = vn[3];
        B4.x = vn[4]; B4.y = vn[5]; B4.z = vn[6]; B4.w = s;
        float4* pp = (float4*)(sm.m.ps + ix * 8);
        pp[0] = A; pp[1] = B4;
      }

      // stage xu: 32 i-rows, vectorized from the padded layout
      const int W = cnt + PT - 1;
      int c0 = p0 + blo;
      c0 %= NLON_O; if (c0 < 0) c0 += NLON_O;      // [0,720)
      const int off = c0 & 3;
      const int a0 = c0 - off;                     // 4-aligned, <= 716
      const int nv = (off + W + 3) >> 2;           // <= 45 float4 per row
      {
        const float4* srcrow = (const float4*)(xu + (size_t)srow * (NLAT_O * XUW) +
                                               (size_t)tp * XUW + a0);
        float4* dstrow = (float4*)(sm.m.xu + srow * XSTR);
        for (int v = scol; v < nv; v += 8) dstrow[v] = srcrow[v];
      }
      __syncthreads();

      macRun(Ga, 0, cnt, off);
      macRun(Gb, 16, cnt, off);
      __syncthreads();
    }

    // ---- GEMM phase: y[o,p] += sum_{i,k} w[o,i,k] * G[k,i,p] ----
    const int op2 = (tid >> 4) << 1;
    const int pc = tid & 15;
    const int pbase2 = 5 * pc;
    float ya[2][5] = {{0.0f}};

    auto gemmHalf = [&](float (&G)[7][5], int hbase) {
#pragma unroll
      for (int k = 0; k < 7; ++k)
#pragma unroll
        for (int jj = 0; jj < 5; ++jj)
          sm.g[(k * 16 + il) * GSTR + pbase + jj] = G[k][jj];
      __syncthreads();
#pragma unroll 1
      for (int ig = 0; ig < 16; ++ig) {
        const float* wp0 = w + op2 * (CI_N * K_N) + (hbase + ig) * K_N;
        const float* wp1 = wp0 + CI_N * K_N;
#pragma unroll
        for (int k = 0; k < 7; ++k) {
          float w0 = wp0[k], w1 = wp1[k];
          const float* gp = sm.g + (k * 16 + ig) * GSTR + pbase2;
#pragma unroll
          for (int jj = 0; jj < 5; ++jj) {
            float gv = gp[jj];
            ya[0][jj] += w0 * gv;
            ya[1][jj] += w1 * gv;
          }
        }
      }
      __syncthreads();
    };
    gemmHalf(Ga, 0);
    gemmHalf(Gb, 16);

#pragma unroll
    for (int oo = 0; oo < 2; ++oo) {
      float* yo = y + (size_t)(op2 + oo) * (NLAT_O * NLON_O) + (size_t)t * NLON_O +
                  p0 + pbase2;
#pragma unroll
      for (int jj = 0; jj < 5; ++jj) atomicAdd(&yo[jj], ya[oo][jj]);
    }
  }
}

// ---------------- launch ----------------------------------------------------
extern "C" void kernel_launch(void* const* d_in, const int* in_sizes, int n_in,
                              void* d_out, int out_size, void* d_ws, size_t ws_size,
                              hipStream_t stream) {
  (void)in_sizes; (void)n_in; (void)out_size; (void)ws_size;
  const float* x = (const float*)d_in[0];
  const float* w = (const float*)d_in[1];
  float* y = (float*)d_out;

  float* xu = (float*)d_ws;                                   // 32*361*896 f32
  float* recip = xu + (size_t)CI_N * NLAT_O * XUW;            // 361*7 f32
  int* counter = (int*)(recip + NLAT_O * K_N);                // 1 int

  hipMemsetAsync(y, 0, (size_t)CO_N * NLAT_O * NLON_O * sizeof(float), stream);

  int n_up = CI_N * NLAT_O * XUW;
  upsample_kernel<<<(n_up + 255) / 256, 256, 0, stream>>>(x, xu, counter);
  scale_kernel<<<NLAT_O, 256, 0, stream>>>(recip);

  disco_kernel<<<NBLOCKS, 256, 0, stream>>>(xu, recip, w, y, counter);
}